// Round 3
// baseline (950.812 us; speedup 1.0000x reference)
//
#include <hip/hip_runtime.h>

typedef __bf16 bf16_t;
typedef __attribute__((ext_vector_type(8))) __bf16 bf16x8;
typedef __attribute__((ext_vector_type(4))) float f32x4;

#define M_DIM 8192   // BSZ*SEQ
#define N_DIM 4096   // OUT_DIM
#define K_DIM 4096   // IN_DIM
#define R_DIM 64     // total rank

// ---------------- kernel 1: x fp32 -> bf16 ----------------
__global__ __launch_bounds__(256) void cvt_x(const float* __restrict__ in,
                                             bf16_t* __restrict__ out) {
    size_t i = ((size_t)blockIdx.x * 256 + threadIdx.x) * 8;
    float4 a = *(const float4*)(in + i);
    float4 b = *(const float4*)(in + i + 4);
    bf16x8 v;
    v[0] = (bf16_t)a.x; v[1] = (bf16_t)a.y; v[2] = (bf16_t)a.z; v[3] = (bf16_t)a.w;
    v[4] = (bf16_t)b.x; v[5] = (bf16_t)b.y; v[6] = (bf16_t)b.z; v[7] = (bf16_t)b.w;
    *(bf16x8*)(out + i) = v;
}

// ------- kernel 2: Weff[o][i] = bf16(W[o][i] + sum_r (2*B[o][r])*A[r][i]) -------
__global__ __launch_bounds__(256) void build_weff(const float* __restrict__ W,
                                                  const float* __restrict__ A,
                                                  const float* __restrict__ Bl,
                                                  bf16_t* __restrict__ out) {
    __shared__ __attribute__((aligned(16))) float bls[16 * R_DIM];  // 4 KiB

    const int i  = blockIdx.x * 256 + threadIdx.x;
    const int o0 = blockIdx.y * 16;

    {   // cooperative stage: 1024 floats / 256 threads = 4 each
        const int t = threadIdx.x;
        float4 v = *(const float4*)(Bl + o0 * R_DIM + t * 4);
        *(float4*)(bls + t * 4) = v;
    }
    __syncthreads();

    float acc[16];
#pragma unroll
    for (int j = 0; j < 16; j++) acc[j] = W[(size_t)(o0 + j) * K_DIM + i];

    for (int rh = 0; rh < R_DIM; rh += 16) {   // NOT unrolled: keeps pressure low
        float av[16];
#pragma unroll
        for (int r = 0; r < 16; r++) av[r] = 2.0f * A[(size_t)(rh + r) * K_DIM + i];
#pragma unroll
        for (int j = 0; j < 16; j++) {
#pragma unroll
            for (int rq = 0; rq < 4; rq++) {
                float4 b = *(const float4*)(bls + j * R_DIM + rh + rq * 4);
                acc[j] = fmaf(b.x, av[rq * 4 + 0], acc[j]);
                acc[j] = fmaf(b.y, av[rq * 4 + 1], acc[j]);
                acc[j] = fmaf(b.z, av[rq * 4 + 2], acc[j]);
                acc[j] = fmaf(b.w, av[rq * 4 + 3], acc[j]);
            }
        }
    }
#pragma unroll
    for (int j = 0; j < 16; j++) out[(size_t)(o0 + j) * K_DIM + i] = (bf16_t)acc[j];
}

// ---------------- kernel 3: C[M][N] = Xb[M][K] * Weff[N][K]^T ----------------
// 256x256 tile, BK=64, 8 waves (2x4), 4 phases/K-tile.
//
// ROUND-3 CHANGE: REG-STAGING (global_load -> VGPR -> ds_write), 2 tiles ahead.
// Rounds 1-2 used global_load_lds + explicit counted vmcnt and landed exactly
// on the drain-0 plateau (302us / MfmaUtil 38) BOTH times, including with
// distinct LDS objects -> the compiler's LDS-DMA handling inserts vmcnt(0)
// before ds_reads categorically; explicit counted waits are dead code.
// With reg-staging every vmem wait is a precise REGISTER dependency: the
// ds_write of tile t+1's data (issued 7 phases earlier) gets a counted
// vmcnt(8)/vmcnt(12) from the compiler (set for t+2 still in flight), and
// ds_read<->ds_write ordering rides lgkmcnt only. No vmcnt asm anywhere.
//
// Pipeline (tile t, phases P1..P4, 16 MFMA each):
//   P1: ds_read B-k0,A-k0(lo); issue 4x global_load A(tile t+2); bar; MFMA; bar
//   P2: ds_read A-k0(hi);      issue 4x global_load B(tile t+2); bar; MFMA; bar
//   P3: ds_read B-k1,A-k1(lo); bar; MFMA; ds_write A(tile t+1)->nxt; bar
//   P4: ds_read A-k1(hi);      bar; MFMA; ds_write B(t+1); lgkmcnt(0); bar
// WAR: buffer written at t.P3/P4 was last read during tile t-1 (>=4 barriers
// earlier). Reg set re-issued (t+2) only after its ds_writes drained (t-1.P4).
#define BM 256
#define BN 256
#define BK 64
#define NT (K_DIM / BK)

#define SBAR() __builtin_amdgcn_s_barrier()
#define LGKM0() asm volatile("s_waitcnt lgkmcnt(0)" ::: "memory")

#define READ_A(ARR, mbase)                                                   \
    _Pragma("unroll")                                                        \
    for (int mf = 0; mf < 4; ++mf)                                           \
        afr[mf] = *(const bf16x8*)(&ARR[0][0] + aoff[(mbase) + mf]);

#define READ_B(ARR)                                                          \
    _Pragma("unroll")                                                        \
    for (int nf = 0; nf < 4; ++nf)                                           \
        bfr[nf] = *(const bf16x8*)(&ARR[0][0] + boff[nf]);

#define MFMA_HALF(mbase)                                                     \
    __builtin_amdgcn_s_setprio(1);                                           \
    _Pragma("unroll")                                                        \
    for (int mf = 0; mf < 4; ++mf)                                           \
        _Pragma("unroll")                                                    \
        for (int nf = 0; nf < 4; ++nf)                                       \
            acc[(mbase) + mf][nf] = __builtin_amdgcn_mfma_f32_16x16x32_bf16( \
                afr[mf], bfr[nf], acc[(mbase) + mf][nf], 0, 0, 0);           \
    __builtin_amdgcn_s_setprio(0);

// issue 4 global 16B loads of one operand tile (2 rows x 2 k-halves), linear
// global addressing (coalesced 64B per 4 lanes). KI in elements.
#define ISSUE(R, P0, P1p, KI)                                                \
    {                                                                        \
        R[0] = *(const bf16x8*)((P0)  + (KI));                               \
        R[1] = *(const bf16x8*)((P1p) + (KI));                               \
        R[2] = *(const bf16x8*)((P0)  + (KI) + 32);                          \
        R[3] = *(const bf16x8*)((P1p) + (KI) + 32);                          \
    }

// write one operand tile into LDS k-half arrays, XOR-swizzled chunk placement
// (write-side swizzle; reads use the same involution -> proven 0-conflict).
#define WRITE(R, D0, D1)                                                     \
    {                                                                        \
        *(bf16x8*)(&D0[0][0] + w0) = R[0];                                   \
        *(bf16x8*)(&D0[0][0] + w1) = R[1];                                   \
        *(bf16x8*)(&D1[0][0] + w0) = R[2];                                   \
        *(bf16x8*)(&D1[0][0] + w1) = R[3];                                   \
    }

// one K-tile: read {RA0,RA1,RB0,RB1}; write reg sets Wa/Wb (tile t+1 data)
// into {WA0,WA1,WB0,WB1}; issue loads for tile t+2 into Ia/Ib at k-off KI.
#define KBODY(RA0, RA1, RB0, RB1, WA0, WA1, WB0, WB1, Wa, Wb, Ia, Ib, KI,    \
              doI, doW)                                                      \
    {                                                                        \
        bf16x8 afr[4], bfr[4];                                               \
        /* P1 */                                                             \
        READ_B(RB0); READ_A(RA0, 0);                                         \
        if (doI) { ISSUE(Ia, pA0, pA1, KI); }                                \
        SBAR(); MFMA_HALF(0); SBAR();                                        \
        /* P2 */                                                             \
        READ_A(RA0, 4);                                                      \
        if (doI) { ISSUE(Ib, pB0, pB1, KI); }                                \
        SBAR(); MFMA_HALF(4); SBAR();                                        \
        /* P3 */                                                             \
        READ_B(RB1); READ_A(RA1, 0);                                         \
        SBAR(); MFMA_HALF(0);                                                \
        if (doW) { WRITE(Wa, WA0, WA1); }                                    \
        SBAR();                                                              \
        /* P4 */                                                             \
        READ_A(RA1, 4);                                                      \
        SBAR(); MFMA_HALF(4);                                                \
        if (doW) { WRITE(Wb, WB0, WB1); LGKM0(); }                           \
        SBAR();                                                              \
    }

__global__ __launch_bounds__(512, 2) void gemm_bf16(const bf16_t* __restrict__ Ax,
                                                    const bf16_t* __restrict__ Bw,
                                                    float* __restrict__ C) {
    // distinct LDS objects: {A,B} x {buf0,buf1} x {khalf0,khalf1}, 16 KiB each
    __shared__ __attribute__((aligned(16))) bf16_t As0a[256][32], As0b[256][32];
    __shared__ __attribute__((aligned(16))) bf16_t As1a[256][32], As1b[256][32];
    __shared__ __attribute__((aligned(16))) bf16_t Bs0a[256][32], Bs0b[256][32];
    __shared__ __attribute__((aligned(16))) bf16_t Bs1a[256][32], Bs1b[256][32];

    const int tid  = threadIdx.x;
    const int wave = (tid >> 6) & 7;
    const int lane = tid & 63;
    const int m16  = lane & 15;
    const int quad = lane >> 4;
    const int wm   = wave >> 2;   // 0..1 -> 128-row half
    const int wn   = wave & 3;    // 0..3 -> 64-col quarter

    // XCD-aware bijective swizzle (512 blocks, 512 % 8 == 0)
    const int fid = blockIdx.y * 16 + blockIdx.x;
    const int swz = (fid & 7) * 64 + (fid >> 3);
    const int m0  = (swz >> 4) * BM;
    const int n0  = (swz & 15) * BN;

    // staging lane geometry: two rows per thread, one 16B chunk each
    const int srow = lane >> 2;            // 0..15
    const int sc   = lane & 3;             // 16B chunk 0..3 within 32-elem half
    const int r0   = wave * 32 + srow;     // rows this thread stages
    const int r1   = r0 + 16;
    const bf16_t* pA0 = Ax + (size_t)(m0 + r0) * K_DIM + sc * 8;
    const bf16_t* pA1 = Ax + (size_t)(m0 + r1) * K_DIM + sc * 8;
    const bf16_t* pB0 = Bw + (size_t)(n0 + r0) * K_DIM + sc * 8;
    const bf16_t* pB1 = Bw + (size_t)(n0 + r1) * K_DIM + sc * 8;
    // swizzled LDS write offsets (elements) within a [256][32] k-half
    const int w0 = r0 * 32 + ((sc ^ ((r0 >> 1) & 3)) << 3);
    const int w1 = r1 * 32 + ((sc ^ ((r1 >> 1) & 3)) << 3);

    // consumption offsets (elements) into a [256][32] k-half
    int aoff[8], boff[4];
#pragma unroll
    for (int mf = 0; mf < 8; ++mf) {
        const int mr = wm * 128 + mf * 16 + m16;
        aoff[mf] = mr * 32 + ((quad ^ ((mr >> 1) & 3)) << 3);
    }
#pragma unroll
    for (int nf = 0; nf < 4; ++nf) {
        const int nr = wn * 64 + nf * 16 + m16;
        boff[nf] = nr * 32 + ((quad ^ ((nr >> 1) & 3)) << 3);
    }

    f32x4 acc[8][4] = {};
    bf16x8 rEa[4], rEb[4], rOa[4], rOb[4];   // staged tiles: even / odd parity

    // prologue: issue tiles 0 (E) and 1 (O); write tile 0 -> buf0.
    // compiler waits are counted here (vmcnt(12)/vmcnt(8)): O-set still flying.
    ISSUE(rEa, pA0, pA1, 0);
    ISSUE(rEb, pB0, pB1, 0);
    ISSUE(rOa, pA0, pA1, BK);
    ISSUE(rOb, pB0, pB1, BK);
    WRITE(rEa, As0a, As0b);
    WRITE(rEb, Bs0a, Bs0b);
    LGKM0();
    SBAR();

#pragma unroll 1
    for (int t = 0; t < NT; t += 2) {
        const int  ki_e = (t + 2) * BK;
        const int  ki_o = (t + 3) * BK;
        const bool di_e = (t + 2) < NT;
        const bool di_o = (t + 3) < NT;
        const bool dw_o = (t + 2) < NT;
        // even tile t: read buf0; write tile t+1 (rO) -> buf1; issue t+2 -> rE
        KBODY(As0a, As0b, Bs0a, Bs0b, As1a, As1b, Bs1a, Bs1b,
              rOa, rOb, rEa, rEb, ki_e, di_e, true);
        // odd tile t+1: read buf1; write tile t+2 (rE) -> buf0; issue t+3 -> rO
        KBODY(As1a, As1b, Bs1a, Bs1b, As0a, As0b, Bs0a, Bs0b,
              rEa, rEb, rOa, rOb, ki_o, di_o, dw_o);
    }

    // epilogue: C/D layout col = lane&15, row = quad*4 + reg
#pragma unroll
    for (int mf = 0; mf < 8; ++mf) {
#pragma unroll
        for (int i = 0; i < 4; ++i) {
            const int gm = m0 + wm * 128 + mf * 16 + quad * 4 + i;
            float* crow = C + (size_t)gm * N_DIM + n0 + wn * 64 + m16;
#pragma unroll
            for (int nf = 0; nf < 4; ++nf)
                crow[nf * 16] = acc[mf][nf][i];
        }
    }
}

extern "C" void kernel_launch(void* const* d_in, const int* in_sizes, int n_in,
                              void* d_out, int out_size, void* d_ws, size_t ws_size,
                              hipStream_t stream) {
    const float* x  = (const float*)d_in[0];
    const float* W  = (const float*)d_in[1];
    const float* La = (const float*)d_in[2];
    const float* Lb = (const float*)d_in[3];
    float* out = (float*)d_out;

    // workspace: xb (64 MiB) | Weff (32 MiB)
    bf16_t* xb = (bf16_t*)d_ws;
    bf16_t* wf = (bf16_t*)((char*)d_ws + (size_t)M_DIM * K_DIM * sizeof(bf16_t));

    cvt_x<<<(M_DIM * K_DIM) / (256 * 8), 256, 0, stream>>>(x, xb);
    build_weff<<<dim3(K_DIM / 256, N_DIM / 16), 256, 0, stream>>>(W, La, Lb, wf);
    gemm_bf16<<<dim3(N_DIM / BN, M_DIM / BM), 512, 0, stream>>>(xb, wf, out);
}